// Round 1
// baseline (5635.864 us; speedup 1.0000x reference)
//
#include <hip/hip_runtime.h>
#include <math.h>

// Problem constants (fixed by the reference).
#define TT   512   // timesteps
#define BI   12    // input features (layer 0)
#define HH   50    // hidden size
#define BB   4     // batch elements per block
#define BTOT 2048  // total batch

// Block = 256 threads = 4 waves.
// wave k (k = tid>>6) owns gate type k (PyTorch order: 0=i, 1=f, 2=g, 3=o).
// lane l (tid&63), active for l < 50, owns hidden unit l.
// Thread (k,l) holds weight rows  w_*[k*50+l][:]  in registers (162 floats).
// h state lives in LDS as [j][b] (16B rows -> one broadcast ds_read_b128
// feeds 4 FMAs). c state for (unit l, batch k) lives in thread (k,l)'s regs.

__launch_bounds__(256, 2)
__global__ void lstm2_kernel(const float* __restrict__ x,
                             const float* __restrict__ w_ih0, const float* __restrict__ w_hh0,
                             const float* __restrict__ b_ih0, const float* __restrict__ b_hh0,
                             const float* __restrict__ w_ih1, const float* __restrict__ w_hh1,
                             const float* __restrict__ b_ih1, const float* __restrict__ b_hh1,
                             const float* __restrict__ w_out, const float* __restrict__ b_out,
                             float* __restrict__ out)
{
    const int tid = threadIdx.x;
    const int k   = tid >> 6;   // wave id = gate type
    const int l   = tid & 63;   // lane = hidden unit
    const int b0  = blockIdx.x * BB;

    __shared__ __align__(16) float h0_lds[HH][BB];
    __shared__ __align__(16) float h1_lds[HH][BB];
    __shared__ __align__(16) float gates_lds[4][HH][BB];

    // ---- persistent per-thread weights (register-resident) ----
    float w0x[BI], w0h[HH], w1x[HH], w1h[HH];
    float bias0 = 0.f, bias1 = 0.f;
    const int row = k * HH + l;
    if (l < HH) {
        #pragma unroll
        for (int i = 0; i < BI; i++) w0x[i] = w_ih0[row * BI + i];
        #pragma unroll
        for (int j = 0; j < HH; j++) w0h[j] = w_hh0[row * HH + j];
        #pragma unroll
        for (int j = 0; j < HH; j++) w1x[j] = w_ih1[row * HH + j];
        #pragma unroll
        for (int j = 0; j < HH; j++) w1h[j] = w_hh1[row * HH + j];
        bias0 = b_ih0[row] + b_hh0[row];
        bias1 = b_ih1[row] + b_hh1[row];
    }

    // zero initial h state
    if (tid < HH * BB) {
        ((float*)h0_lds)[tid] = 0.f;
        ((float*)h1_lds)[tid] = 0.f;
    }
    float c0 = 0.f, c1 = 0.f;   // state for (unit l, batch k)
    __syncthreads();

    for (int t = 0; t < TT; t++) {
        // ---------- phase A: layer-0 gates ----------
        float acc[BB];
        if (l < HH) {
            #pragma unroll
            for (int b = 0; b < BB; b++) acc[b] = bias0;
            // input projection (x addresses are wave-uniform -> scalar loads)
            #pragma unroll
            for (int b = 0; b < BB; b++) {
                const float* xp = x + ((size_t)(b0 + b) * TT + t) * BI;
                #pragma unroll
                for (int i = 0; i < BI; i++) acc[b] += w0x[i] * xp[i];
            }
            // recurrent part: broadcast b128 read of h0[j][0..3]
            #pragma unroll
            for (int j = 0; j < HH; j++) {
                const float4 hv = *(const float4*)(&h0_lds[j][0]);
                acc[0] += w0h[j] * hv.x;
                acc[1] += w0h[j] * hv.y;
                acc[2] += w0h[j] * hv.z;
                acc[3] += w0h[j] * hv.w;
            }
            #pragma unroll
            for (int b = 0; b < BB; b++) gates_lds[k][l][b] = acc[b];
        }
        __syncthreads();

        // ---------- phase B: layer-0 cell update (thread (k,l) -> unit l, batch k) ----------
        if (l < HH) {
            float iv = gates_lds[0][l][k];
            float fv = gates_lds[1][l][k];
            float gv = gates_lds[2][l][k];
            float ov = gates_lds[3][l][k];
            iv = 1.f / (1.f + __expf(-iv));
            fv = 1.f / (1.f + __expf(-fv));
            gv = tanhf(gv);
            ov = 1.f / (1.f + __expf(-ov));
            c0 = fv * c0 + iv * gv;
            h0_lds[l][k] = ov * tanhf(c0);
        }
        __syncthreads();

        // ---------- phase C: layer-1 gates ----------
        if (l < HH) {
            #pragma unroll
            for (int b = 0; b < BB; b++) acc[b] = bias1;
            #pragma unroll
            for (int j = 0; j < HH; j++) {
                const float4 h0v = *(const float4*)(&h0_lds[j][0]);
                acc[0] += w1x[j] * h0v.x;
                acc[1] += w1x[j] * h0v.y;
                acc[2] += w1x[j] * h0v.z;
                acc[3] += w1x[j] * h0v.w;
                const float4 h1v = *(const float4*)(&h1_lds[j][0]);
                acc[0] += w1h[j] * h1v.x;
                acc[1] += w1h[j] * h1v.y;
                acc[2] += w1h[j] * h1v.z;
                acc[3] += w1h[j] * h1v.w;
            }
            #pragma unroll
            for (int b = 0; b < BB; b++) gates_lds[k][l][b] = acc[b];
        }
        __syncthreads();

        // ---------- phase D: layer-1 cell update ----------
        if (l < HH) {
            float iv = gates_lds[0][l][k];
            float fv = gates_lds[1][l][k];
            float gv = gates_lds[2][l][k];
            float ov = gates_lds[3][l][k];
            iv = 1.f / (1.f + __expf(-iv));
            fv = 1.f / (1.f + __expf(-fv));
            gv = tanhf(gv);
            ov = 1.f / (1.f + __expf(-ov));
            c1 = fv * c1 + iv * gv;
            h1_lds[l][k] = ov * tanhf(c1);
        }
        __syncthreads();
    }

    // ---------- epilogue: logits = h1[T-1] . w_out + b_out -> sigmoid ----------
    if (tid < BB) {
        float s = b_out[0];
        #pragma unroll
        for (int j = 0; j < HH; j++) s += w_out[j] * h1_lds[j][tid];
        out[b0 + tid] = 1.f / (1.f + __expf(-s));
    }
}

extern "C" void kernel_launch(void* const* d_in, const int* in_sizes, int n_in,
                              void* d_out, int out_size, void* d_ws, size_t ws_size,
                              hipStream_t stream) {
    const float* x     = (const float*)d_in[0];
    const float* w_ih0 = (const float*)d_in[1];
    const float* w_hh0 = (const float*)d_in[2];
    const float* b_ih0 = (const float*)d_in[3];
    const float* b_hh0 = (const float*)d_in[4];
    const float* w_ih1 = (const float*)d_in[5];
    const float* w_hh1 = (const float*)d_in[6];
    const float* b_ih1 = (const float*)d_in[7];
    const float* b_hh1 = (const float*)d_in[8];
    const float* w_out = (const float*)d_in[9];
    const float* b_out = (const float*)d_in[10];
    float* out = (float*)d_out;

    dim3 grid(BTOT / BB);   // 512 blocks, 4 batch elements each
    dim3 block(256);        // 4 waves: one per gate type
    lstm2_kernel<<<grid, block, 0, stream>>>(x, w_ih0, w_hh0, b_ih0, b_hh0,
                                             w_ih1, w_hh1, b_ih1, b_hh1,
                                             w_out, b_out, out);
}

// Round 2
// 4955.919 us; speedup vs baseline: 1.1372x; 1.1372x over previous
//
#include <hip/hip_runtime.h>
#include <math.h>

// Problem constants (fixed by the reference).
#define TT   512   // timesteps
#define BI   12    // input features (layer 0)
#define HH   50    // hidden size
#define BB   8     // batch elements per block
#define BTOT 2048  // total batch

// Block = 512 threads = 8 waves, 256 blocks (1 per CU).
//   waves 0-3 : layer-0 gate k = wave id   (PyTorch order i,f,g,o)
//   waves 4-7 : layer-1 gate k = wave id-4
// lane l (<50) owns hidden unit l. Layer-0 thread holds 62 weight floats,
// layer-1 thread holds 100 — both fit in VGPRs (launch_bounds(512,1) lifts
// the cap to 512; round-1's 162-float version spilled at cap 128 and paid
// 18 GB of scratch traffic).
//
// The two layers are software-pipelined by one timestep (exact):
//   iter t: layer0 computes h0[t] from h0[t-1],x[t];
//           layer1 computes h1[t-1] from h0[t-1],h1[t-2].
// Loop runs t = 0..TT inclusive so layer1 finishes h1[TT-1].

__device__ __forceinline__ float sigm_(float v) { return 1.f / (1.f + __expf(-v)); }
__device__ __forceinline__ float tanh_(float v) { return 1.f - 2.f / (__expf(2.f * v) + 1.f); }

__launch_bounds__(512, 1)
__global__ void lstm2_kernel(const float* __restrict__ x,
                             const float* __restrict__ w_ih0, const float* __restrict__ w_hh0,
                             const float* __restrict__ b_ih0, const float* __restrict__ b_hh0,
                             const float* __restrict__ w_ih1, const float* __restrict__ w_hh1,
                             const float* __restrict__ b_ih1, const float* __restrict__ b_hh1,
                             const float* __restrict__ w_out, const float* __restrict__ b_out,
                             float* __restrict__ out)
{
    const int tid   = threadIdx.x;
    const int wv    = tid >> 6;        // 0..7
    const int l     = tid & 63;
    const int layer = wv >> 2;         // 0 or 1
    const int k     = wv & 3;          // gate type
    const int b0    = blockIdx.x * BB;
    const int lc    = (l < HH) ? l : (HH - 1);   // clamp so all lanes load (uniform flow)
    const int row   = k * HH + lc;

    __shared__ __align__(16) float h0s[HH][BB];
    __shared__ __align__(16) float h1s[HH][BB];
    __shared__ __align__(16) float g0s[4][HH][BB];
    __shared__ __align__(16) float g1s[4][HH][BB];

    // ---- persistent register-resident weights ----
    float wa[HH], wb[HH];
    float bias;
    if (layer == 0) {
        #pragma unroll
        for (int i = 0; i < BI; i++) wa[i] = w_ih0[row * BI + i];
        #pragma unroll
        for (int j = 0; j < HH; j++) wb[j] = w_hh0[row * HH + j];
        bias = b_ih0[row] + b_hh0[row];
    } else {
        #pragma unroll
        for (int j = 0; j < HH; j++) wa[j] = w_ih1[row * HH + j];
        #pragma unroll
        for (int j = 0; j < HH; j++) wb[j] = w_hh1[row * HH + j];
        bias = b_ih1[row] + b_hh1[row];
    }

    if (tid < HH * BB) {
        ((float*)h0s)[tid] = 0.f;
        ((float*)h1s)[tid] = 0.f;
    }
    float cc0 = 0.f, cc1 = 0.f;              // cell state, batches bsel / bsel+4
    const int bsel = ((l >> 2) + k) & 3;     // swizzled batch pick (bank-spread)
    __syncthreads();

    for (int t = 0; t <= TT; t++) {
        // ---------------- gate phase ----------------
        if (layer == 0) {
            if (t < TT) {
                float acc[BB];
                #pragma unroll
                for (int b = 0; b < BB; b++) acc[b] = bias;
                // input projection: wave-uniform addresses (scalar-cached)
                #pragma unroll
                for (int b = 0; b < BB; b++) {
                    const float4* xp = (const float4*)(x + ((size_t)(b0 + b) * TT + t) * BI);
                    const float4 x0 = xp[0], x1 = xp[1], x2 = xp[2];
                    acc[b] += wa[0] * x0.x + wa[1] * x0.y + wa[2]  * x0.z + wa[3]  * x0.w
                            + wa[4] * x1.x + wa[5] * x1.y + wa[6]  * x1.z + wa[7]  * x1.w
                            + wa[8] * x2.x + wa[9] * x2.y + wa[10] * x2.z + wa[11] * x2.w;
                }
                // recurrent part: broadcast b128 reads of h0[j][0..7]
                #pragma unroll
                for (int j = 0; j < HH; j++) {
                    const float4 ha = *(const float4*)&h0s[j][0];
                    const float4 hb = *(const float4*)&h0s[j][4];
                    const float w = wb[j];
                    acc[0] += w * ha.x; acc[1] += w * ha.y;
                    acc[2] += w * ha.z; acc[3] += w * ha.w;
                    acc[4] += w * hb.x; acc[5] += w * hb.y;
                    acc[6] += w * hb.z; acc[7] += w * hb.w;
                }
                if (l < HH) {
                    *(float4*)&g0s[k][l][0] = make_float4(acc[0], acc[1], acc[2], acc[3]);
                    *(float4*)&g0s[k][l][4] = make_float4(acc[4], acc[5], acc[6], acc[7]);
                }
            }
        } else {
            if (t >= 1) {
                float acc[BB];
                #pragma unroll
                for (int b = 0; b < BB; b++) acc[b] = bias;
                #pragma unroll
                for (int j = 0; j < HH; j++) {
                    const float4 xa = *(const float4*)&h0s[j][0];
                    const float4 xb = *(const float4*)&h0s[j][4];
                    const float wx = wa[j];
                    acc[0] += wx * xa.x; acc[1] += wx * xa.y;
                    acc[2] += wx * xa.z; acc[3] += wx * xa.w;
                    acc[4] += wx * xb.x; acc[5] += wx * xb.y;
                    acc[6] += wx * xb.z; acc[7] += wx * xb.w;
                    const float4 ra = *(const float4*)&h1s[j][0];
                    const float4 rb = *(const float4*)&h1s[j][4];
                    const float wh = wb[j];
                    acc[0] += wh * ra.x; acc[1] += wh * ra.y;
                    acc[2] += wh * ra.z; acc[3] += wh * ra.w;
                    acc[4] += wh * rb.x; acc[5] += wh * rb.y;
                    acc[6] += wh * rb.z; acc[7] += wh * rb.w;
                }
                if (l < HH) {
                    *(float4*)&g1s[k][l][0] = make_float4(acc[0], acc[1], acc[2], acc[3]);
                    *(float4*)&g1s[k][l][4] = make_float4(acc[4], acc[5], acc[6], acc[7]);
                }
            }
        }
        __syncthreads();

        // ---------------- cell-update phase ----------------
        // thread (wave k, lane l<50) updates unit l for batches bsel, bsel+4
        if (l < HH && (layer == 0 ? (t < TT) : (t >= 1))) {
            const int b1 = bsel, b2 = bsel + 4;
            if (layer == 0) {
                float iv = sigm_(g0s[0][l][b1]);
                float fv = sigm_(g0s[1][l][b1]);
                float gv = tanh_(g0s[2][l][b1]);
                float ov = sigm_(g0s[3][l][b1]);
                cc0 = fv * cc0 + iv * gv;
                h0s[l][b1] = ov * tanh_(cc0);
                iv = sigm_(g0s[0][l][b2]);
                fv = sigm_(g0s[1][l][b2]);
                gv = tanh_(g0s[2][l][b2]);
                ov = sigm_(g0s[3][l][b2]);
                cc1 = fv * cc1 + iv * gv;
                h0s[l][b2] = ov * tanh_(cc1);
            } else {
                float iv = sigm_(g1s[0][l][b1]);
                float fv = sigm_(g1s[1][l][b1]);
                float gv = tanh_(g1s[2][l][b1]);
                float ov = sigm_(g1s[3][l][b1]);
                cc0 = fv * cc0 + iv * gv;
                h1s[l][b1] = ov * tanh_(cc0);
                iv = sigm_(g1s[0][l][b2]);
                fv = sigm_(g1s[1][l][b2]);
                gv = tanh_(g1s[2][l][b2]);
                ov = sigm_(g1s[3][l][b2]);
                cc1 = fv * cc1 + iv * gv;
                h1s[l][b2] = ov * tanh_(cc1);
            }
        }
        __syncthreads();
    }

    // ---------------- epilogue: sigmoid(h1[T-1] . w_out + b_out) ----------------
    if (tid < BB) {
        float s = b_out[0];
        #pragma unroll
        for (int j = 0; j < HH; j++) s += w_out[j] * h1s[j][tid];
        out[b0 + tid] = sigm_(s);
    }
}

extern "C" void kernel_launch(void* const* d_in, const int* in_sizes, int n_in,
                              void* d_out, int out_size, void* d_ws, size_t ws_size,
                              hipStream_t stream) {
    const float* x     = (const float*)d_in[0];
    const float* w_ih0 = (const float*)d_in[1];
    const float* w_hh0 = (const float*)d_in[2];
    const float* b_ih0 = (const float*)d_in[3];
    const float* b_hh0 = (const float*)d_in[4];
    const float* w_ih1 = (const float*)d_in[5];
    const float* w_hh1 = (const float*)d_in[6];
    const float* b_ih1 = (const float*)d_in[7];
    const float* b_hh1 = (const float*)d_in[8];
    const float* w_out = (const float*)d_in[9];
    const float* b_out = (const float*)d_in[10];
    float* out = (float*)d_out;

    dim3 grid(BTOT / BB);   // 256 blocks, 8 batch elements each -> 1 block/CU
    dim3 block(512);        // 8 waves: 4 layer-0 gates + 4 layer-1 gates
    lstm2_kernel<<<grid, block, 0, stream>>>(x, w_ih0, w_hh0, b_ih0, b_hh0,
                                             w_ih1, w_hh1, b_ih1, b_hh1,
                                             w_out, b_out, out);
}

// Round 3
// 1988.962 us; speedup vs baseline: 2.8336x; 2.4917x over previous
//
#include <hip/hip_runtime.h>
#include <math.h>

// Problem constants (fixed by the reference).
#define TT   512   // timesteps
#define BI   12    // input features (layer 0)
#define HH   50    // hidden size
#define BB   8     // batch elements per block
#define BTOT 2048  // total batch
#define PADH 12    // padded h row (12 floats = 48B: keeps [u][0]/[u][4] 16B-aligned,
                   // breaks the stride-8 bank aliasing on h writes)

// Block = 1024 threads = 16 waves, 256 blocks (1/CU, 4 waves/SIMD, VGPR cap 128).
// R1/R2 lesson: the allocator caps at 128 VGPRs; per-thread weight state must
// fit WELL under that. So each dot product is split across a lane pair:
//   wave wv: layer = wv>>3, wid = wv&7, gate k = wid>>1, unit-group p = wid&1
//   lane l:  unit u = p*25 + (l>>1)  (active for l<50), j-half s = l&1
// layer-0 thread holds 6 input + 25 recurrent weights (31 floats);
// layer-1 thread holds 25 + 25 (50 floats). Halves combine via __shfl_xor(.,1).
//
// Layers software-pipelined by one timestep (exact), as in R2:
//   iter t: layer0 -> h0[t] from h0[t-1],x[t]; layer1 -> h1[t-1] from h0[t-1],h1[t-2].

__device__ __forceinline__ float sigm_(float v) { return 1.f / (1.f + __expf(-v)); }
__device__ __forceinline__ float tanh_(float v) { return 1.f - 2.f / (__expf(2.f * v) + 1.f); }

__launch_bounds__(1024)
__global__ void lstm2_kernel(const float* __restrict__ x,
                             const float* __restrict__ w_ih0, const float* __restrict__ w_hh0,
                             const float* __restrict__ b_ih0, const float* __restrict__ b_hh0,
                             const float* __restrict__ w_ih1, const float* __restrict__ w_hh1,
                             const float* __restrict__ b_ih1, const float* __restrict__ b_hh1,
                             const float* __restrict__ w_out, const float* __restrict__ b_out,
                             float* __restrict__ out)
{
    const int tid   = threadIdx.x;
    const int wv    = tid >> 6;        // 0..15
    const int l     = tid & 63;
    const int layer = wv >> 3;         // 0 or 1
    const int wid   = wv & 7;
    const int k     = wid >> 1;        // gate (i,f,g,o)
    const int p     = wid & 1;         // unit group
    const int s     = l & 1;           // j-half within the pair
    const int b0    = blockIdx.x * BB;
    const bool act  = (l < 50);
    const int u     = p * 25 + (l >> 1);
    const int uc    = act ? u : (p * 25 + 24);   // clamp for uniform loads
    const int row   = k * HH + uc;

    __shared__ __align__(16) float h0s[HH][PADH];
    __shared__ __align__(16) float h1s[HH][PADH];
    __shared__ float g0s[4][BB][HH];   // [gate][batch][unit] -> stride-1 in u
    __shared__ float g1s[4][BB][HH];

    // ---- persistent half-row weights (register-resident, <=50 floats) ----
    float wr1[25], wr2[25], wx6[6];
    float bias = 0.f;
    if (layer == 0) {
        #pragma unroll
        for (int i = 0; i < 6; i++)  wx6[i] = w_ih0[row * BI + s * 6 + i];
        #pragma unroll
        for (int j = 0; j < 25; j++) wr1[j] = w_hh0[row * HH + s * 25 + j];
        if (s == 0) bias = b_ih0[row] + b_hh0[row];
    } else {
        #pragma unroll
        for (int j = 0; j < 25; j++) wr1[j] = w_ih1[row * HH + s * 25 + j];
        #pragma unroll
        for (int j = 0; j < 25; j++) wr2[j] = w_hh1[row * HH + s * 25 + j];
        if (s == 0) bias = b_ih1[row] + b_hh1[row];
    }

    // ---- cell-update mapping: first 400 threads of each layer own (u,b) ----
    const int t8   = wid * 64 + l;          // 0..511 within layer
    const int ub   = t8 / 50;               // batch
    const int uu2  = t8 - ub * 50;          // unit
    const bool upd = (t8 < 400);
    float cc = 0.f;                          // cell state for (uu2, ub)

    for (int i = tid; i < HH * PADH; i += 1024) {
        ((float*)h0s)[i] = 0.f;
        ((float*)h1s)[i] = 0.f;
    }
    __syncthreads();

    const int hoff = s * 25;   // this half's j-range starts here

    for (int t = 0; t <= TT; t++) {
        // ---------------- gate phase ----------------
        if (layer == 0) {
            if (t < TT) {
                // issue x loads first; j-loop below hides their latency
                float2 xv[BB][3];
                #pragma unroll
                for (int b = 0; b < BB; b++) {
                    const float2* xp = (const float2*)(x + ((size_t)(b0 + b) * TT + t) * BI + s * 6);
                    xv[b][0] = xp[0]; xv[b][1] = xp[1]; xv[b][2] = xp[2];
                }
                float acc[BB];
                #pragma unroll
                for (int b = 0; b < BB; b++) acc[b] = bias;
                #pragma unroll
                for (int j = 0; j < 25; j++) {
                    const float4 a0 = *(const float4*)&h0s[hoff + j][0];
                    const float4 a1 = *(const float4*)&h0s[hoff + j][4];
                    const float w = wr1[j];
                    acc[0] += w * a0.x; acc[1] += w * a0.y; acc[2] += w * a0.z; acc[3] += w * a0.w;
                    acc[4] += w * a1.x; acc[5] += w * a1.y; acc[6] += w * a1.z; acc[7] += w * a1.w;
                }
                #pragma unroll
                for (int b = 0; b < BB; b++) {
                    acc[b] += wx6[0] * xv[b][0].x + wx6[1] * xv[b][0].y
                            + wx6[2] * xv[b][1].x + wx6[3] * xv[b][1].y
                            + wx6[4] * xv[b][2].x + wx6[5] * xv[b][2].y;
                }
                #pragma unroll
                for (int b = 0; b < BB; b++) acc[b] += __shfl_xor(acc[b], 1, 64);
                if (act && s == 0) {
                    #pragma unroll
                    for (int b = 0; b < BB; b++) g0s[k][b][u] = acc[b];
                }
            }
        } else {
            if (t >= 1) {
                float acc[BB];
                #pragma unroll
                for (int b = 0; b < BB; b++) acc[b] = bias;
                #pragma unroll
                for (int j = 0; j < 25; j++) {
                    const float4 a0 = *(const float4*)&h0s[hoff + j][0];
                    const float4 a1 = *(const float4*)&h0s[hoff + j][4];
                    const float wA = wr1[j];
                    acc[0] += wA * a0.x; acc[1] += wA * a0.y; acc[2] += wA * a0.z; acc[3] += wA * a0.w;
                    acc[4] += wA * a1.x; acc[5] += wA * a1.y; acc[6] += wA * a1.z; acc[7] += wA * a1.w;
                    const float4 r0 = *(const float4*)&h1s[hoff + j][0];
                    const float4 r1 = *(const float4*)&h1s[hoff + j][4];
                    const float wB = wr2[j];
                    acc[0] += wB * r0.x; acc[1] += wB * r0.y; acc[2] += wB * r0.z; acc[3] += wB * r0.w;
                    acc[4] += wB * r1.x; acc[5] += wB * r1.y; acc[6] += wB * r1.z; acc[7] += wB * r1.w;
                }
                #pragma unroll
                for (int b = 0; b < BB; b++) acc[b] += __shfl_xor(acc[b], 1, 64);
                if (act && s == 0) {
                    #pragma unroll
                    for (int b = 0; b < BB; b++) g1s[k][b][u] = acc[b];
                }
            }
        }
        __syncthreads();

        // ---------------- cell-update phase ----------------
        if (upd && (layer == 0 ? (t < TT) : (t >= 1))) {
            const float* G = layer ? &g1s[0][0][0] : &g0s[0][0][0];
            const int base = ub * HH + uu2;
            const float iv = sigm_(G[0 * BB * HH + base]);
            const float fv = sigm_(G[1 * BB * HH + base]);
            const float gv = tanh_(G[2 * BB * HH + base]);
            const float ov = sigm_(G[3 * BB * HH + base]);
            cc = fv * cc + iv * gv;
            const float hv = ov * tanh_(cc);
            if (layer) h1s[uu2][ub] = hv; else h0s[uu2][ub] = hv;
        }
        __syncthreads();
    }

    // ---------------- epilogue: sigmoid(h1[T-1] . w_out + b_out) ----------------
    if (tid < BB) {
        float sum = b_out[0];
        #pragma unroll
        for (int j = 0; j < HH; j++) sum += w_out[j] * h1s[j][tid];
        out[b0 + tid] = sigm_(sum);
    }
}

extern "C" void kernel_launch(void* const* d_in, const int* in_sizes, int n_in,
                              void* d_out, int out_size, void* d_ws, size_t ws_size,
                              hipStream_t stream) {
    const float* x     = (const float*)d_in[0];
    const float* w_ih0 = (const float*)d_in[1];
    const float* w_hh0 = (const float*)d_in[2];
    const float* b_ih0 = (const float*)d_in[3];
    const float* b_hh0 = (const float*)d_in[4];
    const float* w_ih1 = (const float*)d_in[5];
    const float* w_hh1 = (const float*)d_in[6];
    const float* b_ih1 = (const float*)d_in[7];
    const float* b_hh1 = (const float*)d_in[8];
    const float* w_out = (const float*)d_in[9];
    const float* b_out = (const float*)d_in[10];
    float* out = (float*)d_out;

    dim3 grid(BTOT / BB);   // 256 blocks -> 1 per CU
    dim3 block(1024);       // 16 waves: 8 layer-0 gate-halves + 8 layer-1
    lstm2_kernel<<<grid, block, 0, stream>>>(x, w_ih0, w_hh0, b_ih0, b_hh0,
                                             w_ih1, w_hh1, b_ih1, b_hh1,
                                             w_out, b_out, out);
}